// Round 7
// baseline (208.073 us; speedup 1.0000x reference)
//
#include <hip/hip_runtime.h>
#include <hip/hip_bf16.h>
#include <stdint.h>

typedef __attribute__((ext_vector_type(8))) short bf16x8;
typedef __attribute__((ext_vector_type(8))) _Float16 f16x8;
typedef __attribute__((ext_vector_type(4))) _Float16 f16x4;
typedef __attribute__((ext_vector_type(2))) _Float16 f16x2;
typedef __attribute__((ext_vector_type(4))) float f32x4;

static constexpr int BATCH = 2;
static constexpr int SEQ = 2048;
static constexpr int EMB = 1024;
static constexpr int NH = 16;
static constexpr int HD_ = 64;

#define AS1 __attribute__((address_space(1)))
#define AS3 __attribute__((address_space(3)))

__device__ __forceinline__ void gload_lds16(const void* g, void* l) {
  __builtin_amdgcn_global_load_lds((const AS1 uint32_t*)g, (AS3 uint32_t*)l, 16, 0, 0);
}

__device__ __forceinline__ f32x4 mfma16(bf16x8 a, bf16x8 b, f32x4 c) {
  return __builtin_amdgcn_mfma_f32_16x16x32_bf16(a, b, c, 0, 0, 0);
}
__device__ __forceinline__ f32x4 mfma16(f16x8 a, f16x8 b, f32x4 c) {
  return __builtin_amdgcn_mfma_f32_16x16x32_f16(a, b, c, 0, 0, 0);
}

// pack two f32 -> 2x f16 (RTZ) as our f16x2 type
__device__ __forceinline__ f16x2 pk16(float a, float b) {
  auto r = __builtin_amdgcn_cvt_pkrtz(a, b);  // __fp16 ext_vector(2)
  return __builtin_bit_cast(f16x2, r);
}

// swizzled 16B-block read from a 128B-row LDS tile: byte ^= (row&7)<<4
__device__ __forceinline__ f16x8 swzread(const _Float16* base, int row, int blk) {
  return *(const f16x8*)((const char*)base + row * 128 +
                         ((blk * 16) ^ ((row & 7) << 4)));
}

template <int MODE> struct elem_of { using t = __hip_bfloat16; };
template <> struct elem_of<1> { using t = _Float16; };
template <typename E> struct v8t;
template <> struct v8t<__hip_bfloat16> { using t = bf16x8; };
template <> struct v8t<_Float16> { using t = f16x8; };

// ---------------- convert f32 -> bf16 hi/lo split ----------------
__global__ __launch_bounds__(256) void k_convert_split(const float* __restrict__ in,
                                                       __hip_bfloat16* __restrict__ oh,
                                                       __hip_bfloat16* __restrict__ ol,
                                                       int n4) {
  int idx = blockIdx.x * 256 + threadIdx.x;
  if (idx >= n4) return;
  float4 v = reinterpret_cast<const float4*>(in)[idx];
  const float* f = reinterpret_cast<const float*>(&v);
  __hip_bfloat16 h[4], l[4];
#pragma unroll
  for (int i = 0; i < 4; ++i) {
    h[i] = __float2bfloat16(f[i]);
    l[i] = __float2bfloat16(f[i] - __bfloat162float(h[i]));
  }
  reinterpret_cast<uint2*>(oh)[idx] = *reinterpret_cast<uint2*>(h);
  reinterpret_cast<uint2*>(ol)[idx] = *reinterpret_cast<uint2*>(l);
}

// ---------------- transpose+convert ----------------
// TM 0: Wqkv -> bf16 hi/lo, rows permuted to [q(1024) | k(1024) | v(1024)]
// TM 1: Wproj -> f16 single, no perm
template <int TM>
__global__ __launch_bounds__(256) void k_transpose(const float* __restrict__ in,
                                                   void* __restrict__ oh_,
                                                   void* __restrict__ ol_, int R, int C) {
  __shared__ float tile[32][33];
  const int t = threadIdx.x;
  const int tr = t >> 5, tc = t & 31;
  const int r0 = blockIdx.y * 32, c0 = blockIdx.x * 32;
#pragma unroll
  for (int rr = 0; rr < 32; rr += 8)
    tile[tr + rr][tc] = in[(size_t)(r0 + tr + rr) * C + c0 + tc];
  __syncthreads();
#pragma unroll
  for (int rr = 0; rr < 32; rr += 8) {
    const int c = c0 + tr + rr;
    const float v = tile[tc][tr + rr];
    if constexpr (TM == 0) {
      const int h = c / 192, r = c - h * 192;
      const int d = (r < 64) ? h * 64 + r
                             : (r < 128 ? 1024 + h * 64 + (r - 64)
                                        : 2048 + h * 64 + (r - 128));
      const __hip_bfloat16 hi = __float2bfloat16(v);
      ((__hip_bfloat16*)oh_)[(size_t)d * R + r0 + tc] = hi;
      ((__hip_bfloat16*)ol_)[(size_t)d * R + r0 + tc] =
          __float2bfloat16(v - __bfloat162float(hi));
    } else {
      ((_Float16*)oh_)[(size_t)c * R + r0 + tc] = (_Float16)v;
    }
  }
}

// ---------------- 128x128 GEMM (A[M][K] * Bt[N][K]^T) ----------------
// MODE 0 (bf16, SPLIT=1): QK epilogue -> q_s f16 (x8*log2e), k_s f16
// MODE 2 (bf16, SPLIT=0): V epilogue -> v_t f16 transposed
// MODE 1 (f16,  SPLIT=0): proj epilogue -> f32 + bias
template <int MODE, int SPLIT>
__global__ __launch_bounds__(256) void k_gemm(
    const void* __restrict__ Ah_, const void* __restrict__ Al_,
    const void* __restrict__ Bh_, const void* __restrict__ Bl_,
    const float* __restrict__ bias, int M, int N, int K, void* __restrict__ o1_,
    void* __restrict__ o2_, float* __restrict__ of) {
  using E = typename elem_of<MODE>::t;
  using V8 = typename v8t<E>::t;
  const E* Ah = (const E*)Ah_;
  const E* Al = (const E*)Al_;
  const E* Bh = (const E*)Bh_;
  const E* Bl = (const E*)Bl_;
  __shared__ E AsH[2][128 * 32];
  __shared__ E BsH[2][128 * 32];
  __shared__ E AsL[SPLIT ? 2 : 1][128 * 32];
  __shared__ E BsL[SPLIT ? 2 : 1][128 * 32];
  const int t = threadIdx.x;
  const int l = t & 63, w = t >> 6;
  const int lr = l & 15, lg = l >> 4;
  const int wr = w >> 1, wc = w & 1;
  const int m0 = blockIdx.y * 128, n0 = blockIdx.x * 128;

  auto stage = [&](int buf, int k0) {
#pragma unroll
    for (int j = 0; j < 2; ++j) {
      const int c = t + 256 * j;
      const int row = c >> 2, cb = c & 3;
      const size_t ga = (size_t)(m0 + row) * K + k0 + cb * 8;
      const size_t gb = (size_t)(n0 + row) * K + k0 + cb * 8;
      gload_lds16(Ah + ga, &AsH[buf][c * 8]);
      gload_lds16(Bh + gb, &BsH[buf][c * 8]);
      if constexpr (SPLIT) {
        gload_lds16(Al + ga, &AsL[buf][c * 8]);
        gload_lds16(Bl + gb, &BsL[buf][c * 8]);
      }
    }
  };

  f32x4 acc[4][4];
#pragma unroll
  for (int m = 0; m < 4; ++m)
#pragma unroll
    for (int n = 0; n < 4; ++n) acc[m][n] = f32x4{0.f, 0.f, 0.f, 0.f};

  stage(0, 0);
  const int NT = K / 32;
  int cur = 0;
  for (int kt = 0; kt < NT; ++kt) {
    __syncthreads();
    if (kt + 1 < NT) stage(cur ^ 1, (kt + 1) * 32);
    V8 afh[4], bfh[4], afl[4], bfl[4];
#pragma unroll
    for (int m = 0; m < 4; ++m) {
      const int off = (wr * 64 + m * 16 + lr) * 32 + lg * 8;
      afh[m] = *(const V8*)&AsH[cur][off];
      if constexpr (SPLIT) afl[m] = *(const V8*)&AsL[cur][off];
    }
#pragma unroll
    for (int n = 0; n < 4; ++n) {
      const int off = (wc * 64 + n * 16 + lr) * 32 + lg * 8;
      bfh[n] = *(const V8*)&BsH[cur][off];
      if constexpr (SPLIT) bfl[n] = *(const V8*)&BsL[cur][off];
    }
#pragma unroll
    for (int m = 0; m < 4; ++m)
#pragma unroll
      for (int n = 0; n < 4; ++n) {
        acc[m][n] = mfma16(afh[m], bfh[n], acc[m][n]);
        if constexpr (SPLIT) {
          acc[m][n] = mfma16(afh[m], bfl[n], acc[m][n]);
          acc[m][n] = mfma16(afl[m], bfh[n], acc[m][n]);
        }
      }
    cur ^= 1;
  }

#pragma unroll
  for (int m = 0; m < 4; ++m) {
#pragma unroll
    for (int n = 0; n < 4; ++n) {
#pragma unroll
      for (int i = 0; i < 4; ++i) {
        const int row = m0 + wr * 64 + m * 16 + lg * 4 + i;
        const int col = n0 + wc * 64 + n * 16 + lr;
        if constexpr (MODE == 0) {
          // cols [0,1024)=q, [1024,2048)=k (permuted W); bias remap to original
          const int cc = col & 1023;
          const int h = cc >> 6, r = cc & 63;
          const float bv = bias[h * 192 + (col < 1024 ? 0 : 64) + r];
          const float v = acc[m][n][i] + bv;
          const int b = row >> 11, s = row & (SEQ - 1);
          const size_t dst = (((size_t)b * NH + h) * SEQ + s) * HD_ + r;
          if (col < 1024)
            ((_Float16*)o1_)[dst] = (_Float16)(v * 11.5415603f);  // q: 8*log2(e) folded
          else
            ((_Float16*)o2_)[dst] = (_Float16)v;  // k
        } else if constexpr (MODE == 2) {
          const int h = col >> 6, r = col & 63;
          const float v = acc[m][n][i] + bias[h * 192 + 128 + r];
          const int b = row >> 11, s = row & (SEQ - 1);
          ((_Float16*)o1_)[(((size_t)b * NH + h) * HD_ + r) * SEQ + s] = (_Float16)v;
        } else {
          of[(size_t)row * N + col] = acc[m][n][i] + bias[col];
        }
      }
    }
  }
}

// ---------------- flash attention, f16, swapped QK^T ----------------
// async-DMA dbuf staging + T21 swizzled LDS, unroll-2 (compile-time buf),
// mr folded into MFMA C-init (no subs in common path), cvt_pkrtz P-pack,
// negligible-tile skip, base-2 softmax with defer-max.
__global__ __launch_bounds__(256) void k_attn(const _Float16* __restrict__ qs,
                                              const _Float16* __restrict__ ks,
                                              const _Float16* __restrict__ vt,
                                              _Float16* __restrict__ ao) {
  __shared__ _Float16 Kt[2][64][64];   // [buf][kv][d]   swizzled rows (128B)
  __shared__ _Float16 Vt[2][64][64];   // [buf][d][kv]   swizzled rows
  __shared__ _Float16 Pl[4][16][64];   // per-wave P [q][kv], swizzled rows
  const int t = threadIdx.x;
  const int l = t & 63, w = t >> 6;
  const int lr = l & 15, lg = l >> 4;
  // XCD-grouping swizzle: 4 whole heads per XCD -> K/V L2-resident
  const int id = blockIdx.x;
  const int xc = id & 7, m_ = id >> 3;
  const int bh = xc + 8 * (m_ >> 5);
  const int qb = (m_ & 31) * 64 + w * 16;

  // Q fragments (B-operand: n=q=lr, k=d)
  const size_t qoff = ((size_t)bh * SEQ + qb + lr) * HD_;
  const f16x8 qf0 = *(const f16x8*)(qs + qoff + lg * 8);
  const f16x8 qf1 = *(const f16x8*)(qs + qoff + 32 + lg * 8);

  const _Float16* kbase = ks + (size_t)bh * SEQ * HD_;
  const _Float16* vbase = vt + (size_t)bh * HD_ * SEQ;

  // async staging: LDS dest linear (= base + t*16, DMA rule); global SOURCE
  // block pre-swizzled so the swizzled read returns original data (T21).
  const int srow = t >> 3, scb = t & 7;
  auto stage = [&](const int buf, const int kv0) {
    const int r0 = srow, r1 = srow + 32;
    gload_lds16(kbase + (size_t)(kv0 + r0) * HD_ + (scb ^ (r0 & 7)) * 8,
                &Kt[buf][r0][scb * 8]);
    gload_lds16(kbase + (size_t)(kv0 + r1) * HD_ + (scb ^ (r1 & 7)) * 8,
                &Kt[buf][r1][scb * 8]);
    gload_lds16(vbase + (size_t)r0 * SEQ + kv0 + (scb ^ (r0 & 7)) * 8,
                &Vt[buf][r0][scb * 8]);
    gload_lds16(vbase + (size_t)r1 * SEQ + kv0 + (scb ^ (r1 & 7)) * 8,
                &Vt[buf][r1][scb * 8]);
  };

  stage(0, 0);

  float mr = 0.f, lsum = 0.f;  // running max (base-2, absolute), running denom
  f32x4 oacc[4];
#pragma unroll
  for (int n = 0; n < 4; ++n) oacc[n] = f32x4{0.f, 0.f, 0.f, 0.f};

  char* plbase = (char*)&Pl[w][0][0];
  const int NT = SEQ / 64;

  auto body = [&](const int cur, const int it) {
    __syncthreads();  // drains vmcnt: buf[cur] DMA complete; prev reads done
    if (it + 1 < NT) stage(cur ^ 1, (it + 1) * 64);

    // S_rel^T = K Q^T - mr  (mr folded into C-init; lane: kv=16t4+4lg+i, q=lr)
    const float nmr = -mr;
    f32x4 sa[4];
    __builtin_amdgcn_s_setprio(1);
#pragma unroll
    for (int t4 = 0; t4 < 4; ++t4) {
      const int r = t4 * 16 + lr;
      const f16x8 kf0 = swzread(&Kt[cur][0][0], r, lg);
      const f16x8 kf1 = swzread(&Kt[cur][0][0], r, lg + 4);
      f32x4 s = mfma16(kf0, qf0, f32x4{nmr, nmr, nmr, nmr});
      sa[t4] = mfma16(kf1, qf1, s);
    }
    __builtin_amdgcn_s_setprio(0);

    // tile max (relative to mr)
    float t01 = fmaxf(fmaxf(sa[0][0], sa[0][1]), fmaxf(sa[0][2], sa[0][3]));
    float t23 = fmaxf(fmaxf(sa[1][0], sa[1][1]), fmaxf(sa[1][2], sa[1][3]));
    float t45 = fmaxf(fmaxf(sa[2][0], sa[2][1]), fmaxf(sa[2][2], sa[2][3]));
    float t67 = fmaxf(fmaxf(sa[3][0], sa[3][1]), fmaxf(sa[3][2], sa[3][3]));
    float tm = fmaxf(fmaxf(t01, t23), fmaxf(t45, t67));
    tm = fmaxf(tm, __shfl_xor(tm, 16));
    tm = fmaxf(tm, __shfl_xor(tm, 32));

    // whole tile negligible vs running max: contributes < 2^-24 relative
    if (__all(tm < -24.0f)) return;

    float ts = 0.f;
    auto emitP = [&](const float d) {
#pragma unroll
      for (int t4 = 0; t4 < 4; ++t4) {
        const float p0 = exp2f(sa[t4][0] - d);
        const float p1 = exp2f(sa[t4][1] - d);
        const float p2 = exp2f(sa[t4][2] - d);
        const float p3 = exp2f(sa[t4][3] - d);
        ts += (p0 + p1) + (p2 + p3);
        const f16x2 lo2 = pk16(p0, p1);
        const f16x2 hi2 = pk16(p2, p3);
        f16x4 pp;
        pp[0] = lo2[0]; pp[1] = lo2[1]; pp[2] = hi2[0]; pp[3] = hi2[1];
        *(f16x4*)(plbase + lr * 128 + ((t4 * 32 + lg * 8) ^ ((lr & 7) << 4))) = pp;
      }
    };

    if (__any(tm > 8.0f)) {  // rescale (rare after warmup, defer-max THR=8)
      const float nm = fmaxf(tm, 0.f);  // per-lane relative new max
      const float corr = exp2f(-nm);
      mr += nm;
      lsum *= corr;
      float cb4[4];
#pragma unroll
      for (int i = 0; i < 4; ++i)
        cb4[i] = __shfl(corr, (l & 48) + ((l >> 4) << 2) + i);
#pragma unroll
      for (int n = 0; n < 4; ++n)
#pragma unroll
        for (int i = 0; i < 4; ++i) oacc[n][i] *= cb4[i];
      emitP(nm);
    } else {
      emitP(0.0f);  // constant-folds: no subtract in common path
    }

    ts += __shfl_xor(ts, 16);
    ts += __shfl_xor(ts, 32);
    lsum += ts;

    // O += P V (A=P[q][kv], B=V^T[d][kv])
    const f16x8 aP0 = swzread(&Pl[w][0][0], lr, lg);
    const f16x8 aP1 = swzread(&Pl[w][0][0], lr, lg + 4);
    __builtin_amdgcn_s_setprio(1);
#pragma unroll
    for (int n = 0; n < 4; ++n) {
      const int d = n * 16 + lr;
      const f16x8 bv0 = swzread(&Vt[cur][0][0], d, lg);
      const f16x8 bv1 = swzread(&Vt[cur][0][0], d, lg + 4);
      oacc[n] = mfma16(aP0, bv0, oacc[n]);
      oacc[n] = mfma16(aP1, bv1, oacc[n]);
    }
    __builtin_amdgcn_s_setprio(0);
  };

  // unroll-2: buf index compile-time -> all LDS addresses loop-invariant
  for (int it = 0; it < NT; it += 2) {
    body(0, it);
    body(1, it + 1);
  }

  // epilogue: fetch lsum for q=4*lg+i, normalize (rcp), store f16
  float ls4[4];
#pragma unroll
  for (int i = 0; i < 4; ++i)
    ls4[i] = __builtin_amdgcn_rcpf(
        __shfl(lsum, (l & 48) + ((l >> 4) << 2) + i));
  const int b = bh >> 4, h = bh & 15;
#pragma unroll
  for (int n = 0; n < 4; ++n)
#pragma unroll
    for (int i = 0; i < 4; ++i) {
      const int row = qb + ((l >> 4) << 2) + i;
      ao[((size_t)b * SEQ + row) * EMB + h * HD_ + n * 16 + lr] =
          (_Float16)(oacc[n][i] * ls4[i]);
    }
}

extern "C" void kernel_launch(void* const* d_in, const int* in_sizes, int n_in,
                              void* d_out, int out_size, void* d_ws, size_t ws_size,
                              hipStream_t stream) {
  const float* query = (const float*)d_in[0];
  const float* Wqkv = (const float*)d_in[3];
  const float* bqkv = (const float*)d_in[4];
  const float* Wproj = (const float*)d_in[5];
  const float* bproj = (const float*)d_in[6];
  float* out = (float*)d_out;

  char* ws = (char*)d_ws;
  const size_t MB = 1024 * 1024;
  __hip_bfloat16* q_hi    = (__hip_bfloat16*)(ws + 0);        // 8MB; dead after QKV GEMMs
  __hip_bfloat16* q_lo    = (__hip_bfloat16*)(ws + 8 * MB);   // 8MB; dead after QK GEMM
  __hip_bfloat16* Wqkv_th = (__hip_bfloat16*)(ws + 16 * MB);  // 6MB (rows: q|k|v)
  __hip_bfloat16* Wqkv_tl = (__hip_bfloat16*)(ws + 22 * MB);  // 6MB
  _Float16* q_s           = (_Float16*)(ws + 28 * MB);        // 8MB [32][2048][64]
  _Float16* k_s           = (_Float16*)(ws + 36 * MB);        // 8MB
  _Float16* v_t           = (_Float16*)(ws + 44 * MB);        // 8MB [32][64][2048]
  _Float16* a_o           = (_Float16*)(ws + 0);              // aliases q_hi
  _Float16* Wproj_t       = (_Float16*)(ws + 8 * MB);         // aliases q_lo

  const int M = BATCH * SEQ;  // 4096
  k_convert_split<<<(M * EMB / 4 + 255) / 256, 256, 0, stream>>>(query, q_hi, q_lo,
                                                                 M * EMB / 4);
  k_transpose<0><<<dim3(3 * EMB / 32, EMB / 32), 256, 0, stream>>>(Wqkv, Wqkv_th,
                                                                   Wqkv_tl, EMB, 3 * EMB);
  // q,k columns: split-bf16 precision (3 MFMA)
  k_gemm<0, 1><<<dim3(16, M / 128), 256, 0, stream>>>(
      q_hi, q_lo, Wqkv_th, Wqkv_tl, bqkv, M, 2048, EMB, q_s, k_s, nullptr);
  // v columns: single bf16 (1 MFMA)
  k_gemm<2, 0><<<dim3(8, M / 128), 256, 0, stream>>>(
      q_hi, nullptr, Wqkv_th + (size_t)2048 * EMB, nullptr, bqkv, M, 1024, EMB, v_t,
      nullptr, nullptr);
  k_transpose<1><<<dim3(EMB / 32, EMB / 32), 256, 0, stream>>>(Wproj, Wproj_t, nullptr,
                                                               EMB, EMB);
  k_attn<<<dim3(1024), 256, 0, stream>>>(q_s, k_s, v_t, a_o);
  k_gemm<1, 0><<<dim3(EMB / 128, M / 128), 256, 0, stream>>>(
      a_o, nullptr, Wproj_t, nullptr, bproj, M, EMB, EMB, nullptr, nullptr, out);
}

// Round 8
// 186.800 us; speedup vs baseline: 1.1139x; 1.1139x over previous
//
#include <hip/hip_runtime.h>
#include <hip/hip_bf16.h>
#include <stdint.h>

typedef __attribute__((ext_vector_type(8))) short bf16x8;
typedef __attribute__((ext_vector_type(8))) _Float16 f16x8;
typedef __attribute__((ext_vector_type(4))) _Float16 f16x4;
typedef __attribute__((ext_vector_type(4))) float f32x4;

static constexpr int BATCH = 2;
static constexpr int SEQ = 2048;
static constexpr int EMB = 1024;
static constexpr int NH = 16;
static constexpr int HD_ = 64;

#define AS1 __attribute__((address_space(1)))
#define AS3 __attribute__((address_space(3)))

__device__ __forceinline__ void gload_lds16(const void* g, void* l) {
  __builtin_amdgcn_global_load_lds((const AS1 uint32_t*)g, (AS3 uint32_t*)l, 16, 0, 0);
}

__device__ __forceinline__ f32x4 mfma16(bf16x8 a, bf16x8 b, f32x4 c) {
  return __builtin_amdgcn_mfma_f32_16x16x32_bf16(a, b, c, 0, 0, 0);
}
__device__ __forceinline__ f32x4 mfma16(f16x8 a, f16x8 b, f32x4 c) {
  return __builtin_amdgcn_mfma_f32_16x16x32_f16(a, b, c, 0, 0, 0);
}

// swizzled 16B-block read from a 128B-row LDS tile: byte ^= (row&7)<<4
__device__ __forceinline__ f16x8 swzread(const _Float16* base, int row, int blk) {
  return *(const f16x8*)((const char*)base + row * 128 +
                         ((blk * 16) ^ ((row & 7) << 4)));
}

template <int MODE> struct elem_of { using t = __hip_bfloat16; };
template <> struct elem_of<1> { using t = _Float16; };
template <typename E> struct v8t;
template <> struct v8t<__hip_bfloat16> { using t = bf16x8; };
template <> struct v8t<_Float16> { using t = f16x8; };

// ---------------- convert f32 -> bf16 hi/lo split ----------------
__global__ __launch_bounds__(256) void k_convert_split(const float* __restrict__ in,
                                                       __hip_bfloat16* __restrict__ oh,
                                                       __hip_bfloat16* __restrict__ ol,
                                                       int n4) {
  int idx = blockIdx.x * 256 + threadIdx.x;
  if (idx >= n4) return;
  float4 v = reinterpret_cast<const float4*>(in)[idx];
  const float* f = reinterpret_cast<const float*>(&v);
  __hip_bfloat16 h[4], l[4];
#pragma unroll
  for (int i = 0; i < 4; ++i) {
    h[i] = __float2bfloat16(f[i]);
    l[i] = __float2bfloat16(f[i] - __bfloat162float(h[i]));
  }
  reinterpret_cast<uint2*>(oh)[idx] = *reinterpret_cast<uint2*>(h);
  reinterpret_cast<uint2*>(ol)[idx] = *reinterpret_cast<uint2*>(l);
}

// ---------------- transpose+convert ----------------
// TM 0: Wqkv -> bf16 hi/lo, rows permuted to [q(1024) | k(1024) | v(1024)]
// TM 1: Wproj -> f16 single, no perm
template <int TM>
__global__ __launch_bounds__(256) void k_transpose(const float* __restrict__ in,
                                                   void* __restrict__ oh_,
                                                   void* __restrict__ ol_, int R, int C) {
  __shared__ float tile[32][33];
  const int t = threadIdx.x;
  const int tr = t >> 5, tc = t & 31;
  const int r0 = blockIdx.y * 32, c0 = blockIdx.x * 32;
#pragma unroll
  for (int rr = 0; rr < 32; rr += 8)
    tile[tr + rr][tc] = in[(size_t)(r0 + tr + rr) * C + c0 + tc];
  __syncthreads();
#pragma unroll
  for (int rr = 0; rr < 32; rr += 8) {
    const int c = c0 + tr + rr;
    const float v = tile[tc][tr + rr];
    if constexpr (TM == 0) {
      const int h = c / 192, r = c - h * 192;
      const int d = (r < 64) ? h * 64 + r
                             : (r < 128 ? 1024 + h * 64 + (r - 64)
                                        : 2048 + h * 64 + (r - 128));
      const __hip_bfloat16 hi = __float2bfloat16(v);
      ((__hip_bfloat16*)oh_)[(size_t)d * R + r0 + tc] = hi;
      ((__hip_bfloat16*)ol_)[(size_t)d * R + r0 + tc] =
          __float2bfloat16(v - __bfloat162float(hi));
    } else {
      ((_Float16*)oh_)[(size_t)c * R + r0 + tc] = (_Float16)v;
    }
  }
}

// ---------------- 128x128 GEMM (A[M][K] * Bt[N][K]^T) ----------------
// MODE 0 (bf16, SPLIT=1): QK epilogue -> q_s f16 (x8*log2e), k_s f16
// MODE 2 (bf16, SPLIT=0): V epilogue -> v_t f16 transposed
// MODE 1 (f16,  SPLIT=0): proj epilogue -> f32 + bias
template <int MODE, int SPLIT>
__global__ __launch_bounds__(256) void k_gemm(
    const void* __restrict__ Ah_, const void* __restrict__ Al_,
    const void* __restrict__ Bh_, const void* __restrict__ Bl_,
    const float* __restrict__ bias, int M, int N, int K, void* __restrict__ o1_,
    void* __restrict__ o2_, float* __restrict__ of) {
  using E = typename elem_of<MODE>::t;
  using V8 = typename v8t<E>::t;
  const E* Ah = (const E*)Ah_;
  const E* Al = (const E*)Al_;
  const E* Bh = (const E*)Bh_;
  const E* Bl = (const E*)Bl_;
  __shared__ E AsH[2][128 * 32];
  __shared__ E BsH[2][128 * 32];
  __shared__ E AsL[SPLIT ? 2 : 1][128 * 32];
  __shared__ E BsL[SPLIT ? 2 : 1][128 * 32];
  const int t = threadIdx.x;
  const int l = t & 63, w = t >> 6;
  const int lr = l & 15, lg = l >> 4;
  const int wr = w >> 1, wc = w & 1;
  const int m0 = blockIdx.y * 128, n0 = blockIdx.x * 128;

  auto stage = [&](int buf, int k0) {
#pragma unroll
    for (int j = 0; j < 2; ++j) {
      const int c = t + 256 * j;
      const int row = c >> 2, cb = c & 3;
      const size_t ga = (size_t)(m0 + row) * K + k0 + cb * 8;
      const size_t gb = (size_t)(n0 + row) * K + k0 + cb * 8;
      gload_lds16(Ah + ga, &AsH[buf][c * 8]);
      gload_lds16(Bh + gb, &BsH[buf][c * 8]);
      if constexpr (SPLIT) {
        gload_lds16(Al + ga, &AsL[buf][c * 8]);
        gload_lds16(Bl + gb, &BsL[buf][c * 8]);
      }
    }
  };

  f32x4 acc[4][4];
#pragma unroll
  for (int m = 0; m < 4; ++m)
#pragma unroll
    for (int n = 0; n < 4; ++n) acc[m][n] = f32x4{0.f, 0.f, 0.f, 0.f};

  stage(0, 0);
  const int NT = K / 32;
  int cur = 0;
  for (int kt = 0; kt < NT; ++kt) {
    __syncthreads();
    if (kt + 1 < NT) stage(cur ^ 1, (kt + 1) * 32);
    V8 afh[4], bfh[4], afl[4], bfl[4];
#pragma unroll
    for (int m = 0; m < 4; ++m) {
      const int off = (wr * 64 + m * 16 + lr) * 32 + lg * 8;
      afh[m] = *(const V8*)&AsH[cur][off];
      if constexpr (SPLIT) afl[m] = *(const V8*)&AsL[cur][off];
    }
#pragma unroll
    for (int n = 0; n < 4; ++n) {
      const int off = (wc * 64 + n * 16 + lr) * 32 + lg * 8;
      bfh[n] = *(const V8*)&BsH[cur][off];
      if constexpr (SPLIT) bfl[n] = *(const V8*)&BsL[cur][off];
    }
#pragma unroll
    for (int m = 0; m < 4; ++m)
#pragma unroll
      for (int n = 0; n < 4; ++n) {
        acc[m][n] = mfma16(afh[m], bfh[n], acc[m][n]);
        if constexpr (SPLIT) {
          acc[m][n] = mfma16(afh[m], bfl[n], acc[m][n]);
          acc[m][n] = mfma16(afl[m], bfh[n], acc[m][n]);
        }
      }
    cur ^= 1;
  }

#pragma unroll
  for (int m = 0; m < 4; ++m) {
#pragma unroll
    for (int n = 0; n < 4; ++n) {
#pragma unroll
      for (int i = 0; i < 4; ++i) {
        const int row = m0 + wr * 64 + m * 16 + lg * 4 + i;
        const int col = n0 + wc * 64 + n * 16 + lr;
        if constexpr (MODE == 0) {
          // cols [0,1024)=q, [1024,2048)=k (permuted W); bias remap to original
          const int cc = col & 1023;
          const int h = cc >> 6, r = cc & 63;
          const float bv = bias[h * 192 + (col < 1024 ? 0 : 64) + r];
          const float v = acc[m][n][i] + bv;
          const int b = row >> 11, s = row & (SEQ - 1);
          const size_t dst = (((size_t)b * NH + h) * SEQ + s) * HD_ + r;
          if (col < 1024)
            ((_Float16*)o1_)[dst] = (_Float16)(v * 11.5415603f);  // q: 8*log2(e) folded
          else
            ((_Float16*)o2_)[dst] = (_Float16)v;  // k
        } else if constexpr (MODE == 2) {
          const int h = col >> 6, r = col & 63;
          const float v = acc[m][n][i] + bias[h * 192 + 128 + r];
          const int b = row >> 11, s = row & (SEQ - 1);
          ((_Float16*)o1_)[(((size_t)b * NH + h) * HD_ + r) * SEQ + s] = (_Float16)v;
        } else {
          of[(size_t)row * N + col] = acc[m][n][i] + bias[col];
        }
      }
    }
  }
}

// ---------------- flash attention, f16, swapped QK^T ----------------
// R5 per-wave body (proven 95.3us, 52 VGPR) at 8-wave/128-row blocks:
// one K/V tile DMA feeds 8 waves (staging per q-row halved), grid 512,
// 48KB LDS -> 2 blocks/CU = 16 waves/CU.
__global__ __launch_bounds__(512) void k_attn(const _Float16* __restrict__ qs,
                                              const _Float16* __restrict__ ks,
                                              const _Float16* __restrict__ vt,
                                              _Float16* __restrict__ ao) {
  __shared__ _Float16 Kt[2][64][64];   // [buf][kv][d]   swizzled rows (128B)
  __shared__ _Float16 Vt[2][64][64];   // [buf][d][kv]   swizzled rows
  __shared__ _Float16 Pl[8][16][64];   // per-wave P [q][kv], swizzled rows
  const int t = threadIdx.x;
  const int l = t & 63, w = t >> 6;          // w in [0,8)
  const int lr = l & 15, lg = l >> 4;
  // XCD-grouping swizzle: 512 blocks; id&7 -> XCD; 4 whole heads per XCD
  const int id = blockIdx.x;
  const int xc = id & 7, m_ = id >> 3;       // m_ in [0,64)
  const int bh = xc + 8 * (m_ >> 4);         // 4 heads per XCD
  const int qb = (m_ & 15) * 128 + w * 16;   // 128 q-rows per block

  // Q fragments (B-operand: n=q=lr, k=d)
  const size_t qoff = ((size_t)bh * SEQ + qb + lr) * HD_;
  const f16x8 qf0 = *(const f16x8*)(qs + qoff + lg * 8);
  const f16x8 qf1 = *(const f16x8*)(qs + qoff + 32 + lg * 8);

  const _Float16* kbase = ks + (size_t)bh * SEQ * HD_;
  const _Float16* vbase = vt + (size_t)bh * HD_ * SEQ;

  // async staging: 512 threads cover the 64x64 tile in ONE pass each for K,V.
  // LDS dest linear (DMA rule); global SOURCE block pre-swizzled (T21).
  const int srow = t >> 3, scb = t & 7;      // srow in [0,64)
  auto stage = [&](const int buf, const int kv0) {
    gload_lds16(kbase + (size_t)(kv0 + srow) * HD_ + (scb ^ (srow & 7)) * 8,
                &Kt[buf][srow][scb * 8]);
    gload_lds16(vbase + (size_t)srow * SEQ + kv0 + (scb ^ (srow & 7)) * 8,
                &Vt[buf][srow][scb * 8]);
  };

  stage(0, 0);

  float mr = -1e30f, lsum = 0.f;
  f32x4 oacc[4];
#pragma unroll
  for (int n = 0; n < 4; ++n) oacc[n] = f32x4{0.f, 0.f, 0.f, 0.f};

  const int NT = SEQ / 64;
  for (int it = 0; it < NT; ++it) {
    const int cur = it & 1;
    __syncthreads();  // drains vmcnt: buf[cur] DMA complete; prev reads done
    if (it + 1 < NT) stage(cur ^ 1, (it + 1) * 64);

    // S^T = K Q^T : lane holds S[kv=16*t4+4*lg+i][q=lr]   (base-2 logits)
    f32x4 sa[4];
    __builtin_amdgcn_s_setprio(1);
#pragma unroll
    for (int t4 = 0; t4 < 4; ++t4) {
      const int r = t4 * 16 + lr;
      const f16x8 kf0 = swzread(&Kt[cur][0][0], r, lg);
      const f16x8 kf1 = swzread(&Kt[cur][0][0], r, lg + 4);
      f32x4 s = mfma16(kf0, qf0, f32x4{0.f, 0.f, 0.f, 0.f});
      sa[t4] = mfma16(kf1, qf1, s);
    }
    __builtin_amdgcn_s_setprio(0);

    // online softmax (per-lane q-row), defer-max with THR=8 (base-2)
    float t01 = fmaxf(fmaxf(sa[0][0], sa[0][1]), fmaxf(sa[0][2], sa[0][3]));
    float t23 = fmaxf(fmaxf(sa[1][0], sa[1][1]), fmaxf(sa[1][2], sa[1][3]));
    float t45 = fmaxf(fmaxf(sa[2][0], sa[2][1]), fmaxf(sa[2][2], sa[2][3]));
    float t67 = fmaxf(fmaxf(sa[3][0], sa[3][1]), fmaxf(sa[3][2], sa[3][3]));
    float tm = fmaxf(fmaxf(t01, t23), fmaxf(t45, t67));
    tm = fmaxf(tm, __shfl_xor(tm, 16));
    tm = fmaxf(tm, __shfl_xor(tm, 32));

    if (__any(tm > mr + 8.0f)) {  // wave-uniform rescale
      const float nm = fmaxf(mr, tm);
      const float corr = exp2f(mr - nm);
      mr = nm;
      lsum *= corr;
      float cb4[4];
#pragma unroll
      for (int i = 0; i < 4; ++i)
        cb4[i] = __shfl(corr, (l & 48) + ((l >> 4) << 2) + i);
#pragma unroll
      for (int n = 0; n < 4; ++n)
#pragma unroll
        for (int i = 0; i < 4; ++i) oacc[n][i] *= cb4[i];
    }

    float ts = 0.f;
    char* plbase = (char*)&Pl[w][0][0];
#pragma unroll
    for (int t4 = 0; t4 < 4; ++t4) {
      f16x4 pp;
#pragma unroll
      for (int i = 0; i < 4; ++i) {
        const float p = exp2f(sa[t4][i] - mr);
        ts += p;
        pp[i] = (_Float16)p;
      }
      // P[q=lr][kv=t4*16+lg*4+i], swizzled row (XOR bits 4-6, 8B aligned)
      *(f16x4*)(plbase + lr * 128 + ((t4 * 32 + lg * 8) ^ ((lr & 7) << 4))) = pp;
    }
    ts += __shfl_xor(ts, 16);
    ts += __shfl_xor(ts, 32);
    lsum += ts;

    // O += P V (A=P[q][kv], B=V^T[d][kv])
    const f16x8 aP0 = swzread(&Pl[w][0][0], lr, lg);
    const f16x8 aP1 = swzread(&Pl[w][0][0], lr, lg + 4);
    __builtin_amdgcn_s_setprio(1);
#pragma unroll
    for (int n = 0; n < 4; ++n) {
      const int d = n * 16 + lr;
      const f16x8 bv0 = swzread(&Vt[cur][0][0], d, lg);
      const f16x8 bv1 = swzread(&Vt[cur][0][0], d, lg + 4);
      oacc[n] = mfma16(aP0, bv0, oacc[n]);
      oacc[n] = mfma16(aP1, bv1, oacc[n]);
    }
    __builtin_amdgcn_s_setprio(0);
  }

  // epilogue: fetch lsum for q=4*lg+i, normalize, store f16
  float ls4[4];
#pragma unroll
  for (int i = 0; i < 4; ++i)
    ls4[i] = __shfl(lsum, (l & 48) + ((l >> 4) << 2) + i);
  const int b = bh >> 4, h = bh & 15;
#pragma unroll
  for (int n = 0; n < 4; ++n)
#pragma unroll
    for (int i = 0; i < 4; ++i) {
      const int row = qb + ((l >> 4) << 2) + i;
      ao[((size_t)b * SEQ + row) * EMB + h * HD_ + n * 16 + lr] =
          (_Float16)(oacc[n][i] / ls4[i]);
    }
}

extern "C" void kernel_launch(void* const* d_in, const int* in_sizes, int n_in,
                              void* d_out, int out_size, void* d_ws, size_t ws_size,
                              hipStream_t stream) {
  const float* query = (const float*)d_in[0];
  const float* Wqkv = (const float*)d_in[3];
  const float* bqkv = (const float*)d_in[4];
  const float* Wproj = (const float*)d_in[5];
  const float* bproj = (const float*)d_in[6];
  float* out = (float*)d_out;

  char* ws = (char*)d_ws;
  const size_t MB = 1024 * 1024;
  __hip_bfloat16* q_hi    = (__hip_bfloat16*)(ws + 0);        // 8MB; dead after QKV GEMMs
  __hip_bfloat16* q_lo    = (__hip_bfloat16*)(ws + 8 * MB);   // 8MB; dead after QK GEMM
  __hip_bfloat16* Wqkv_th = (__hip_bfloat16*)(ws + 16 * MB);  // 6MB (rows: q|k|v)
  __hip_bfloat16* Wqkv_tl = (__hip_bfloat16*)(ws + 22 * MB);  // 6MB
  _Float16* q_s           = (_Float16*)(ws + 28 * MB);        // 8MB [32][2048][64]
  _Float16* k_s           = (_Float16*)(ws + 36 * MB);        // 8MB
  _Float16* v_t           = (_Float16*)(ws + 44 * MB);        // 8MB [32][64][2048]
  _Float16* a_o           = (_Float16*)(ws + 0);              // aliases q_hi
  _Float16* Wproj_t       = (_Float16*)(ws + 8 * MB);         // aliases q_lo

  const int M = BATCH * SEQ;  // 4096
  k_convert_split<<<(M * EMB / 4 + 255) / 256, 256, 0, stream>>>(query, q_hi, q_lo,
                                                                 M * EMB / 4);
  k_transpose<0><<<dim3(3 * EMB / 32, EMB / 32), 256, 0, stream>>>(Wqkv, Wqkv_th,
                                                                   Wqkv_tl, EMB, 3 * EMB);
  // q,k columns: split-bf16 precision (3 MFMA)
  k_gemm<0, 1><<<dim3(16, M / 128), 256, 0, stream>>>(
      q_hi, q_lo, Wqkv_th, Wqkv_tl, bqkv, M, 2048, EMB, q_s, k_s, nullptr);
  // v columns: single bf16 (1 MFMA)
  k_gemm<2, 0><<<dim3(8, M / 128), 256, 0, stream>>>(
      q_hi, nullptr, Wqkv_th + (size_t)2048 * EMB, nullptr, bqkv, M, 1024, EMB, v_t,
      nullptr, nullptr);
  k_transpose<1><<<dim3(EMB / 32, EMB / 32), 256, 0, stream>>>(Wproj, Wproj_t, nullptr,
                                                               EMB, EMB);
  k_attn<<<dim3(512), 512, 0, stream>>>(q_s, k_s, v_t, a_o);
  k_gemm<1, 0><<<dim3(EMB / 128, M / 128), 256, 0, stream>>>(
      a_o, nullptr, Wproj_t, nullptr, bproj, M, EMB, EMB, nullptr, nullptr, out);
}

// Round 9
// 167.944 us; speedup vs baseline: 1.2389x; 1.1123x over previous
//
#include <hip/hip_runtime.h>
#include <hip/hip_bf16.h>
#include <stdint.h>

typedef __attribute__((ext_vector_type(8))) _Float16 f16x8;
typedef __attribute__((ext_vector_type(4))) _Float16 f16x4;
typedef __attribute__((ext_vector_type(4))) float f32x4;

static constexpr int BATCH = 2;
static constexpr int SEQ = 2048;
static constexpr int EMB = 1024;
static constexpr int NH = 16;
static constexpr int HD_ = 64;

#define AS1 __attribute__((address_space(1)))
#define AS3 __attribute__((address_space(3)))

__device__ __forceinline__ void gload_lds16(const void* g, void* l) {
  __builtin_amdgcn_global_load_lds((const AS1 uint32_t*)g, (AS3 uint32_t*)l, 16, 0, 0);
}

__device__ __forceinline__ f32x4 mfma16(f16x8 a, f16x8 b, f32x4 c) {
  return __builtin_amdgcn_mfma_f32_16x16x32_f16(a, b, c, 0, 0, 0);
}

// swizzled 16B-block read from a 128B-row LDS tile: byte ^= (row&7)<<4
__device__ __forceinline__ f16x8 swzread(const _Float16* base, int row, int blk) {
  return *(const f16x8*)((const char*)base + row * 128 +
                         ((blk * 16) ^ ((row & 7) << 4)));
}

// ---------------- convert f32 -> f16 hi/lo split (hi+lo ~ 22 mantissa bits) ----------------
__global__ __launch_bounds__(256) void k_convert_split(const float* __restrict__ in,
                                                       _Float16* __restrict__ oh,
                                                       _Float16* __restrict__ ol,
                                                       int n4) {
  int idx = blockIdx.x * 256 + threadIdx.x;
  if (idx >= n4) return;
  float4 v = reinterpret_cast<const float4*>(in)[idx];
  const float* f = reinterpret_cast<const float*>(&v);
  _Float16 h[4], l[4];
#pragma unroll
  for (int i = 0; i < 4; ++i) {
    h[i] = (_Float16)f[i];
    l[i] = (_Float16)(f[i] - (float)h[i]);
  }
  reinterpret_cast<uint2*>(oh)[idx] = *reinterpret_cast<uint2*>(h);
  reinterpret_cast<uint2*>(ol)[idx] = *reinterpret_cast<uint2*>(l);
}

// ---------------- transpose+convert to f16: in[R][C] f32 -> out[perm(C)][R] ----------------
// PERM 1: Wqkv column permutation to [q(1024) | k(1024) | v(1024)]
template <int PERM>
__global__ __launch_bounds__(256) void k_transpose(const float* __restrict__ in,
                                                   _Float16* __restrict__ out, int R,
                                                   int C) {
  __shared__ float tile[32][33];
  const int t = threadIdx.x;
  const int tr = t >> 5, tc = t & 31;
  const int r0 = blockIdx.y * 32, c0 = blockIdx.x * 32;
#pragma unroll
  for (int rr = 0; rr < 32; rr += 8)
    tile[tr + rr][tc] = in[(size_t)(r0 + tr + rr) * C + c0 + tc];
  __syncthreads();
#pragma unroll
  for (int rr = 0; rr < 32; rr += 8) {
    const int c = c0 + tr + rr;
    int d = c;
    if constexpr (PERM) {
      const int h = c / 192, r = c - h * 192;
      d = (r < 64) ? h * 64 + r
                   : (r < 128 ? 1024 + h * 64 + (r - 64) : 2048 + h * 64 + (r - 128));
    }
    out[(size_t)d * R + r0 + tc] = (_Float16)tile[tc][tr + rr];
  }
}

// ---------------- fused QKV GEMM: A(hi/lo f16)[4096][1024] x Bt f16[3072][1024]^T ----------
// cols [0,1024)=q (2-MFMA split), [1024,2048)=k (2-MFMA split), [2048,3072)=v (1-MFMA)
// epilogue scatter: q_s f16 (x 8*log2e), k_s f16, v_t f16 transposed
__global__ __launch_bounds__(256) void k_gemm_qkv(
    const _Float16* __restrict__ Ah, const _Float16* __restrict__ Al,
    const _Float16* __restrict__ Bt, const float* __restrict__ bias,
    _Float16* __restrict__ oq, _Float16* __restrict__ ok,
    _Float16* __restrict__ ov) {
  constexpr int K = EMB;
  __shared__ _Float16 AsH[2][128 * 32];
  __shared__ _Float16 AsL[2][128 * 32];
  __shared__ _Float16 Bs[2][128 * 32];
  const int t = threadIdx.x;
  const int l = t & 63, w = t >> 6;
  const int lr = l & 15, lg = l >> 4;
  const int wr = w >> 1, wc = w & 1;
  const int m0 = blockIdx.y * 128, n0 = blockIdx.x * 128;
  const bool splitb = (n0 < 2048);  // block-uniform (128 | 1024)

  auto stage = [&](int buf, int k0) {
#pragma unroll
    for (int j = 0; j < 2; ++j) {
      const int c = t + 256 * j;
      const int row = c >> 2, cb = c & 3;
      const size_t ga = (size_t)(m0 + row) * K + k0 + cb * 8;
      const size_t gb = (size_t)(n0 + row) * K + k0 + cb * 8;
      gload_lds16(Ah + ga, &AsH[buf][c * 8]);
      gload_lds16(Bt + gb, &Bs[buf][c * 8]);
      if (splitb) gload_lds16(Al + ga, &AsL[buf][c * 8]);
    }
  };

  f32x4 acc[4][4];
#pragma unroll
  for (int m = 0; m < 4; ++m)
#pragma unroll
    for (int n = 0; n < 4; ++n) acc[m][n] = f32x4{0.f, 0.f, 0.f, 0.f};

  stage(0, 0);
  const int NT = K / 32;
  int cur = 0;
  for (int kt = 0; kt < NT; ++kt) {
    __syncthreads();
    if (kt + 1 < NT) stage(cur ^ 1, (kt + 1) * 32);
    f16x8 afh[4], afl[4], bf[4];
#pragma unroll
    for (int m = 0; m < 4; ++m) {
      const int off = (wr * 64 + m * 16 + lr) * 32 + lg * 8;
      afh[m] = *(const f16x8*)&AsH[cur][off];
      if (splitb) afl[m] = *(const f16x8*)&AsL[cur][off];
    }
#pragma unroll
    for (int n = 0; n < 4; ++n)
      bf[n] = *(const f16x8*)&Bs[cur][(wc * 64 + n * 16 + lr) * 32 + lg * 8];
#pragma unroll
    for (int m = 0; m < 4; ++m)
#pragma unroll
      for (int n = 0; n < 4; ++n) {
        acc[m][n] = mfma16(afh[m], bf[n], acc[m][n]);
        if (splitb) acc[m][n] = mfma16(afl[m], bf[n], acc[m][n]);
      }
    cur ^= 1;
  }

#pragma unroll
  for (int m = 0; m < 4; ++m) {
#pragma unroll
    for (int n = 0; n < 4; ++n) {
#pragma unroll
      for (int i = 0; i < 4; ++i) {
        const int row = m0 + wr * 64 + m * 16 + lg * 4 + i;
        const int col = n0 + wc * 64 + n * 16 + lr;
        const int cc = col & 1023;
        const int h = cc >> 6, r = cc & 63;
        const int sec = col >> 10;  // 0=q 1=k 2=v (block-uniform)
        const float v = acc[m][n][i] + bias[h * 192 + sec * 64 + r];
        const int b = row >> 11, s = row & (SEQ - 1);
        if (sec == 0)
          oq[(((size_t)b * NH + h) * SEQ + s) * HD_ + r] =
              (_Float16)(v * 11.5415603f);  // 8*log2(e) folded
        else if (sec == 1)
          ok[(((size_t)b * NH + h) * SEQ + s) * HD_ + r] = (_Float16)v;
        else
          ov[(((size_t)b * NH + h) * HD_ + r) * SEQ + s] = (_Float16)v;  // V^T
      }
    }
  }
}

// ---------------- proj GEMM: a_o f16 x Wproj_t f16^T -> f32 + bias ----------------
__global__ __launch_bounds__(256) void k_gemm_proj(const _Float16* __restrict__ A,
                                                   const _Float16* __restrict__ Bt,
                                                   const float* __restrict__ bias,
                                                   float* __restrict__ of) {
  constexpr int K = EMB, N = EMB;
  __shared__ _Float16 As[2][128 * 32];
  __shared__ _Float16 Bs[2][128 * 32];
  const int t = threadIdx.x;
  const int l = t & 63, w = t >> 6;
  const int lr = l & 15, lg = l >> 4;
  const int wr = w >> 1, wc = w & 1;
  const int m0 = blockIdx.y * 128, n0 = blockIdx.x * 128;

  auto stage = [&](int buf, int k0) {
#pragma unroll
    for (int j = 0; j < 2; ++j) {
      const int c = t + 256 * j;
      const int row = c >> 2, cb = c & 3;
      gload_lds16(A + (size_t)(m0 + row) * K + k0 + cb * 8, &As[buf][c * 8]);
      gload_lds16(Bt + (size_t)(n0 + row) * K + k0 + cb * 8, &Bs[buf][c * 8]);
    }
  };

  f32x4 acc[4][4];
#pragma unroll
  for (int m = 0; m < 4; ++m)
#pragma unroll
    for (int n = 0; n < 4; ++n) acc[m][n] = f32x4{0.f, 0.f, 0.f, 0.f};

  stage(0, 0);
  const int NT = K / 32;
  int cur = 0;
  for (int kt = 0; kt < NT; ++kt) {
    __syncthreads();
    if (kt + 1 < NT) stage(cur ^ 1, (kt + 1) * 32);
    f16x8 af[4], bf[4];
#pragma unroll
    for (int m = 0; m < 4; ++m)
      af[m] = *(const f16x8*)&As[cur][(wr * 64 + m * 16 + lr) * 32 + lg * 8];
#pragma unroll
    for (int n = 0; n < 4; ++n)
      bf[n] = *(const f16x8*)&Bs[cur][(wc * 64 + n * 16 + lr) * 32 + lg * 8];
#pragma unroll
    for (int m = 0; m < 4; ++m)
#pragma unroll
      for (int n = 0; n < 4; ++n) acc[m][n] = mfma16(af[m], bf[n], acc[m][n]);
    cur ^= 1;
  }

#pragma unroll
  for (int m = 0; m < 4; ++m)
#pragma unroll
    for (int n = 0; n < 4; ++n)
#pragma unroll
      for (int i = 0; i < 4; ++i) {
        const int row = m0 + wr * 64 + m * 16 + lg * 4 + i;
        const int col = n0 + wc * 64 + n * 16 + lr;
        of[(size_t)row * N + col] = acc[m][n][i] + bias[col];
      }
}

// ---------------- flash attention (R8, proven 80.6us): f16, swapped QK^T ----------------
// 8-wave/128-row blocks; one K/V tile DMA feeds 8 waves; 48KB LDS; T21 swizzle.
__global__ __launch_bounds__(512) void k_attn(const _Float16* __restrict__ qs,
                                              const _Float16* __restrict__ ks,
                                              const _Float16* __restrict__ vt,
                                              _Float16* __restrict__ ao) {
  __shared__ _Float16 Kt[2][64][64];   // [buf][kv][d]   swizzled rows (128B)
  __shared__ _Float16 Vt[2][64][64];   // [buf][d][kv]   swizzled rows
  __shared__ _Float16 Pl[8][16][64];   // per-wave P [q][kv], swizzled rows
  const int t = threadIdx.x;
  const int l = t & 63, w = t >> 6;          // w in [0,8)
  const int lr = l & 15, lg = l >> 4;
  // XCD-grouping swizzle: 512 blocks; id&7 -> XCD; 4 whole heads per XCD
  const int id = blockIdx.x;
  const int xc = id & 7, m_ = id >> 3;       // m_ in [0,64)
  const int bh = xc + 8 * (m_ >> 4);         // 4 heads per XCD
  const int qb = (m_ & 15) * 128 + w * 16;   // 128 q-rows per block

  // Q fragments (B-operand: n=q=lr, k=d)
  const size_t qoff = ((size_t)bh * SEQ + qb + lr) * HD_;
  const f16x8 qf0 = *(const f16x8*)(qs + qoff + lg * 8);
  const f16x8 qf1 = *(const f16x8*)(qs + qoff + 32 + lg * 8);

  const _Float16* kbase = ks + (size_t)bh * SEQ * HD_;
  const _Float16* vbase = vt + (size_t)bh * HD_ * SEQ;

  // async staging: 512 threads cover the 64x64 tile in ONE pass each for K,V.
  // LDS dest linear (DMA rule); global SOURCE block pre-swizzled (T21).
  const int srow = t >> 3, scb = t & 7;      // srow in [0,64)
  auto stage = [&](const int buf, const int kv0) {
    gload_lds16(kbase + (size_t)(kv0 + srow) * HD_ + (scb ^ (srow & 7)) * 8,
                &Kt[buf][srow][scb * 8]);
    gload_lds16(vbase + (size_t)srow * SEQ + kv0 + (scb ^ (srow & 7)) * 8,
                &Vt[buf][srow][scb * 8]);
  };

  stage(0, 0);

  float mr = -1e30f, lsum = 0.f;
  f32x4 oacc[4];
#pragma unroll
  for (int n = 0; n < 4; ++n) oacc[n] = f32x4{0.f, 0.f, 0.f, 0.f};

  const int NT = SEQ / 64;
  for (int it = 0; it < NT; ++it) {
    const int cur = it & 1;
    __syncthreads();  // drains vmcnt: buf[cur] DMA complete; prev reads done
    if (it + 1 < NT) stage(cur ^ 1, (it + 1) * 64);

    // S^T = K Q^T : lane holds S[kv=16*t4+4*lg+i][q=lr]   (base-2 logits)
    f32x4 sa[4];
    __builtin_amdgcn_s_setprio(1);
#pragma unroll
    for (int t4 = 0; t4 < 4; ++t4) {
      const int r = t4 * 16 + lr;
      const f16x8 kf0 = swzread(&Kt[cur][0][0], r, lg);
      const f16x8 kf1 = swzread(&Kt[cur][0][0], r, lg + 4);
      f32x4 s = mfma16(kf0, qf0, f32x4{0.f, 0.f, 0.f, 0.f});
      sa[t4] = mfma16(kf1, qf1, s);
    }
    __builtin_amdgcn_s_setprio(0);

    // online softmax (per-lane q-row), defer-max with THR=8 (base-2)
    float t01 = fmaxf(fmaxf(sa[0][0], sa[0][1]), fmaxf(sa[0][2], sa[0][3]));
    float t23 = fmaxf(fmaxf(sa[1][0], sa[1][1]), fmaxf(sa[1][2], sa[1][3]));
    float t45 = fmaxf(fmaxf(sa[2][0], sa[2][1]), fmaxf(sa[2][2], sa[2][3]));
    float t67 = fmaxf(fmaxf(sa[3][0], sa[3][1]), fmaxf(sa[3][2], sa[3][3]));
    float tm = fmaxf(fmaxf(t01, t23), fmaxf(t45, t67));
    tm = fmaxf(tm, __shfl_xor(tm, 16));
    tm = fmaxf(tm, __shfl_xor(tm, 32));

    if (__any(tm > mr + 8.0f)) {  // wave-uniform rescale
      const float nm = fmaxf(mr, tm);
      const float corr = exp2f(mr - nm);
      mr = nm;
      lsum *= corr;
      float cb4[4];
#pragma unroll
      for (int i = 0; i < 4; ++i)
        cb4[i] = __shfl(corr, (l & 48) + ((l >> 4) << 2) + i);
#pragma unroll
      for (int n = 0; n < 4; ++n)
#pragma unroll
        for (int i = 0; i < 4; ++i) oacc[n][i] *= cb4[i];
    }

    float ts = 0.f;
    char* plbase = (char*)&Pl[w][0][0];
#pragma unroll
    for (int t4 = 0; t4 < 4; ++t4) {
      f16x4 pp;
#pragma unroll
      for (int i = 0; i < 4; ++i) {
        const float p = exp2f(sa[t4][i] - mr);
        ts += p;
        pp[i] = (_Float16)p;
      }
      // P[q=lr][kv=t4*16+lg*4+i], swizzled row (XOR bits 4-6, 8B aligned)
      *(f16x4*)(plbase + lr * 128 + ((t4 * 32 + lg * 8) ^ ((lr & 7) << 4))) = pp;
    }
    ts += __shfl_xor(ts, 16);
    ts += __shfl_xor(ts, 32);
    lsum += ts;

    // O += P V (A=P[q][kv], B=V^T[d][kv])
    const f16x8 aP0 = swzread(&Pl[w][0][0], lr, lg);
    const f16x8 aP1 = swzread(&Pl[w][0][0], lr, lg + 4);
    __builtin_amdgcn_s_setprio(1);
#pragma unroll
    for (int n = 0; n < 4; ++n) {
      const int d = n * 16 + lr;
      const f16x8 bv0 = swzread(&Vt[cur][0][0], d, lg);
      const f16x8 bv1 = swzread(&Vt[cur][0][0], d, lg + 4);
      oacc[n] = mfma16(aP0, bv0, oacc[n]);
      oacc[n] = mfma16(aP1, bv1, oacc[n]);
    }
    __builtin_amdgcn_s_setprio(0);
  }

  // epilogue: fetch lsum for q=4*lg+i, normalize, store f16
  float ls4[4];
#pragma unroll
  for (int i = 0; i < 4; ++i)
    ls4[i] = __shfl(lsum, (l & 48) + ((l >> 4) << 2) + i);
  const int b = bh >> 4, h = bh & 15;
#pragma unroll
  for (int n = 0; n < 4; ++n)
#pragma unroll
    for (int i = 0; i < 4; ++i) {
      const int row = qb + ((l >> 4) << 2) + i;
      ao[((size_t)b * SEQ + row) * EMB + h * HD_ + n * 16 + lr] =
          (_Float16)(oacc[n][i] / ls4[i]);
    }
}

extern "C" void kernel_launch(void* const* d_in, const int* in_sizes, int n_in,
                              void* d_out, int out_size, void* d_ws, size_t ws_size,
                              hipStream_t stream) {
  const float* query = (const float*)d_in[0];
  const float* Wqkv = (const float*)d_in[3];
  const float* bqkv = (const float*)d_in[4];
  const float* Wproj = (const float*)d_in[5];
  const float* bproj = (const float*)d_in[6];
  float* out = (float*)d_out;

  char* ws = (char*)d_ws;
  const size_t MB = 1024 * 1024;
  _Float16* q_hi    = (_Float16*)(ws + 0);        // 8MB; dead after QKV GEMM
  _Float16* q_lo    = (_Float16*)(ws + 8 * MB);   // 8MB; dead after QKV GEMM
  _Float16* Wqkv_t  = (_Float16*)(ws + 16 * MB);  // 6MB f16 (rows: q|k|v)
  _Float16* q_s     = (_Float16*)(ws + 24 * MB);  // 8MB [32][2048][64]
  _Float16* k_s     = (_Float16*)(ws + 32 * MB);  // 8MB
  _Float16* v_t     = (_Float16*)(ws + 40 * MB);  // 8MB [32][64][2048]
  _Float16* a_o     = (_Float16*)(ws + 0);        // aliases q_hi
  _Float16* Wproj_t = (_Float16*)(ws + 8 * MB);   // aliases q_lo

  const int M = BATCH * SEQ;  // 4096
  k_convert_split<<<(M * EMB / 4 + 255) / 256, 256, 0, stream>>>(query, q_hi, q_lo,
                                                                 M * EMB / 4);
  k_transpose<1><<<dim3(3 * EMB / 32, EMB / 32), 256, 0, stream>>>(Wqkv, Wqkv_t, EMB,
                                                                   3 * EMB);
  k_gemm_qkv<<<dim3(24, M / 128), 256, 0, stream>>>(q_hi, q_lo, Wqkv_t, bqkv, q_s, k_s,
                                                    v_t);
  k_transpose<0><<<dim3(EMB / 32, EMB / 32), 256, 0, stream>>>(Wproj, Wproj_t, EMB, EMB);
  k_attn<<<dim3(512), 512, 0, stream>>>(q_s, k_s, v_t, a_o);
  k_gemm_proj<<<dim3(EMB / 128, M / 128), 256, 0, stream>>>(a_o, Wproj_t, bproj, out);
}

// Round 10
// 165.609 us; speedup vs baseline: 1.2564x; 1.0141x over previous
//
#include <hip/hip_runtime.h>
#include <hip/hip_bf16.h>
#include <stdint.h>

typedef __attribute__((ext_vector_type(8))) _Float16 f16x8;
typedef __attribute__((ext_vector_type(4))) _Float16 f16x4;
typedef __attribute__((ext_vector_type(4))) float f32x4;

static constexpr int BATCH = 2;
static constexpr int SEQ = 2048;
static constexpr int EMB = 1024;
static constexpr int NH = 16;
static constexpr int HD_ = 64;

#define AS1 __attribute__((address_space(1)))
#define AS3 __attribute__((address_space(3)))

__device__ __forceinline__ void gload_lds16(const void* g, void* l) {
  __builtin_amdgcn_global_load_lds((const AS1 uint32_t*)g, (AS3 uint32_t*)l, 16, 0, 0);
}

__device__ __forceinline__ f32x4 mfma16(f16x8 a, f16x8 b, f32x4 c) {
  return __builtin_amdgcn_mfma_f32_16x16x32_f16(a, b, c, 0, 0, 0);
}

// swizzled 16B-block read from a 128B-row LDS tile: byte ^= (row&7)<<4
__device__ __forceinline__ f16x8 swzread(const _Float16* base, int row, int blk) {
  return *(const f16x8*)((const char*)base + row * 128 +
                         ((blk * 16) ^ ((row & 7) << 4)));
}

// ---------------- convert f32 -> f16 hi/lo split (hi+lo ~ 22 mantissa bits) ----------------
__global__ __launch_bounds__(256) void k_convert_split(const float* __restrict__ in,
                                                       _Float16* __restrict__ oh,
                                                       _Float16* __restrict__ ol,
                                                       int n4) {
  int idx = blockIdx.x * 256 + threadIdx.x;
  if (idx >= n4) return;
  float4 v = reinterpret_cast<const float4*>(in)[idx];
  const float* f = reinterpret_cast<const float*>(&v);
  _Float16 h[4], l[4];
#pragma unroll
  for (int i = 0; i < 4; ++i) {
    h[i] = (_Float16)f[i];
    l[i] = (_Float16)(f[i] - (float)h[i]);
  }
  reinterpret_cast<uint2*>(oh)[idx] = *reinterpret_cast<uint2*>(h);
  reinterpret_cast<uint2*>(ol)[idx] = *reinterpret_cast<uint2*>(l);
}

// ---------------- transpose+convert to f16: in[R][C] f32 -> out[perm(C)][R] ----------------
// PERM 1: Wqkv column permutation to [q(1024) | k(1024) | v(1024)]
template <int PERM>
__global__ __launch_bounds__(256) void k_transpose(const float* __restrict__ in,
                                                   _Float16* __restrict__ out, int R,
                                                   int C) {
  __shared__ float tile[32][33];
  const int t = threadIdx.x;
  const int tr = t >> 5, tc = t & 31;
  const int r0 = blockIdx.y * 32, c0 = blockIdx.x * 32;
#pragma unroll
  for (int rr = 0; rr < 32; rr += 8)
    tile[tr + rr][tc] = in[(size_t)(r0 + tr + rr) * C + c0 + tc];
  __syncthreads();
#pragma unroll
  for (int rr = 0; rr < 32; rr += 8) {
    const int c = c0 + tr + rr;
    int d = c;
    if constexpr (PERM) {
      const int h = c / 192, r = c - h * 192;
      d = (r < 64) ? h * 64 + r
                   : (r < 128 ? 1024 + h * 64 + (r - 64) : 2048 + h * 64 + (r - 128));
    }
    out[(size_t)d * R + r0 + tc] = (_Float16)tile[tc][tr + rr];
  }
}

// ---------------- fused QKV GEMM: A(hi/lo f16)[4096][1024] x Bt f16[3072][1024]^T ----------
// cols [0,1024)=q (2-MFMA split), [1024,2048)=k (2-MFMA split), [2048,3072)=v (1-MFMA)
// epilogue scatter: q_s f16 (x 8*log2e), k_s f16, v_t f16 transposed (f16x4 stores)
__global__ __launch_bounds__(256) void k_gemm_qkv(
    const _Float16* __restrict__ Ah, const _Float16* __restrict__ Al,
    const _Float16* __restrict__ Bt, const float* __restrict__ bias,
    _Float16* __restrict__ oq, _Float16* __restrict__ ok,
    _Float16* __restrict__ ov) {
  constexpr int K = EMB;
  __shared__ _Float16 AsH[2][128 * 32];
  __shared__ _Float16 AsL[2][128 * 32];
  __shared__ _Float16 Bs[2][128 * 32];
  const int t = threadIdx.x;
  const int l = t & 63, w = t >> 6;
  const int lr = l & 15, lg = l >> 4;
  const int wr = w >> 1, wc = w & 1;
  const int m0 = blockIdx.y * 128, n0 = blockIdx.x * 128;
  const bool splitb = (n0 < 2048);  // block-uniform

  auto stage = [&](int buf, int k0) {
#pragma unroll
    for (int j = 0; j < 2; ++j) {
      const int c = t + 256 * j;
      const int row = c >> 2, cb = c & 3;
      const size_t ga = (size_t)(m0 + row) * K + k0 + cb * 8;
      const size_t gb = (size_t)(n0 + row) * K + k0 + cb * 8;
      gload_lds16(Ah + ga, &AsH[buf][c * 8]);
      gload_lds16(Bt + gb, &Bs[buf][c * 8]);
      if (splitb) gload_lds16(Al + ga, &AsL[buf][c * 8]);
    }
  };

  f32x4 acc[4][4];
#pragma unroll
  for (int m = 0; m < 4; ++m)
#pragma unroll
    for (int n = 0; n < 4; ++n) acc[m][n] = f32x4{0.f, 0.f, 0.f, 0.f};

  stage(0, 0);
  const int NT = K / 32;
  int cur = 0;
  for (int kt = 0; kt < NT; ++kt) {
    __syncthreads();
    if (kt + 1 < NT) stage(cur ^ 1, (kt + 1) * 32);
    f16x8 afh[4], afl[4], bf[4];
#pragma unroll
    for (int m = 0; m < 4; ++m) {
      const int off = (wr * 64 + m * 16 + lr) * 32 + lg * 8;
      afh[m] = *(const f16x8*)&AsH[cur][off];
      if (splitb) afl[m] = *(const f16x8*)&AsL[cur][off];
    }
#pragma unroll
    for (int n = 0; n < 4; ++n)
      bf[n] = *(const f16x8*)&Bs[cur][(wc * 64 + n * 16 + lr) * 32 + lg * 8];
#pragma unroll
    for (int m = 0; m < 4; ++m)
#pragma unroll
      for (int n = 0; n < 4; ++n) {
        acc[m][n] = mfma16(afh[m], bf[n], acc[m][n]);
        if (splitb) acc[m][n] = mfma16(afl[m], bf[n], acc[m][n]);
      }
    cur ^= 1;
  }

  const int sec = n0 >> 10;  // 0=q 1=k 2=v (block-uniform)
#pragma unroll
  for (int m = 0; m < 4; ++m) {
#pragma unroll
    for (int n = 0; n < 4; ++n) {
      const int col = n0 + wc * 64 + n * 16 + lr;
      const int cc = col & 1023;
      const int h = cc >> 6, r = cc & 63;
      const float bv = bias[h * 192 + sec * 64 + r];
      const int row0 = m0 + wr * 64 + m * 16 + lg * 4;
      const int b = row0 >> 11, s0 = row0 & (SEQ - 1);
      if (sec == 2) {  // V^T: i -> s consecutive, 4-aligned -> one 8B store
        f16x4 vv;
#pragma unroll
        for (int i = 0; i < 4; ++i) vv[i] = (_Float16)(acc[m][n][i] + bv);
        *(f16x4*)&ov[(((size_t)b * NH + h) * HD_ + r) * SEQ + s0] = vv;
      } else {
#pragma unroll
        for (int i = 0; i < 4; ++i) {
          const float v = acc[m][n][i] + bv;
          const size_t dst = (((size_t)b * NH + h) * SEQ + s0 + i) * HD_ + r;
          if (sec == 0)
            oq[dst] = (_Float16)(v * 11.5415603f);  // 8*log2(e) folded
          else
            ok[dst] = (_Float16)v;
        }
      }
    }
  }
}

// ---------------- proj GEMM: a_o f16 x Wproj_t f16^T -> f32 + bias ----------------
__global__ __launch_bounds__(256) void k_gemm_proj(const _Float16* __restrict__ A,
                                                   const _Float16* __restrict__ Bt,
                                                   const float* __restrict__ bias,
                                                   float* __restrict__ of) {
  constexpr int K = EMB, N = EMB;
  __shared__ _Float16 As[2][128 * 32];
  __shared__ _Float16 Bs[2][128 * 32];
  const int t = threadIdx.x;
  const int l = t & 63, w = t >> 6;
  const int lr = l & 15, lg = l >> 4;
  const int wr = w >> 1, wc = w & 1;
  const int m0 = blockIdx.y * 128, n0 = blockIdx.x * 128;

  auto stage = [&](int buf, int k0) {
#pragma unroll
    for (int j = 0; j < 2; ++j) {
      const int c = t + 256 * j;
      const int row = c >> 2, cb = c & 3;
      gload_lds16(A + (size_t)(m0 + row) * K + k0 + cb * 8, &As[buf][c * 8]);
      gload_lds16(Bt + (size_t)(n0 + row) * K + k0 + cb * 8, &Bs[buf][c * 8]);
    }
  };

  f32x4 acc[4][4];
#pragma unroll
  for (int m = 0; m < 4; ++m)
#pragma unroll
    for (int n = 0; n < 4; ++n) acc[m][n] = f32x4{0.f, 0.f, 0.f, 0.f};

  stage(0, 0);
  const int NT = K / 32;
  int cur = 0;
  for (int kt = 0; kt < NT; ++kt) {
    __syncthreads();
    if (kt + 1 < NT) stage(cur ^ 1, (kt + 1) * 32);
    f16x8 af[4], bf[4];
#pragma unroll
    for (int m = 0; m < 4; ++m)
      af[m] = *(const f16x8*)&As[cur][(wr * 64 + m * 16 + lr) * 32 + lg * 8];
#pragma unroll
    for (int n = 0; n < 4; ++n)
      bf[n] = *(const f16x8*)&Bs[cur][(wc * 64 + n * 16 + lr) * 32 + lg * 8];
#pragma unroll
    for (int m = 0; m < 4; ++m)
#pragma unroll
      for (int n = 0; n < 4; ++n) acc[m][n] = mfma16(af[m], bf[n], acc[m][n]);
    cur ^= 1;
  }

#pragma unroll
  for (int m = 0; m < 4; ++m)
#pragma unroll
    for (int n = 0; n < 4; ++n)
#pragma unroll
      for (int i = 0; i < 4; ++i) {
        const int row = m0 + wr * 64 + m * 16 + lg * 4 + i;
        const int col = n0 + wc * 64 + n * 16 + lr;
        of[(size_t)row * N + col] = acc[m][n][i] + bias[col];
      }
}

// ---------------- flash attention, KV-split: R8 body, half the KV range ------------
// grid 1024: (bh, 128 q-rows, kv-half). Emits unnormalized partial O (f16) +
// per-row (m, lsum). 48KB LDS -> 3 blocks/CU (was grid-capped at 2).
__global__ __launch_bounds__(512) void k_attn(
    const _Float16* __restrict__ qs, const _Float16* __restrict__ ks,
    const _Float16* __restrict__ vt, _Float16* __restrict__ op,
    float* __restrict__ marr, float* __restrict__ larr) {
  __shared__ _Float16 Kt[2][64][64];   // [buf][kv][d]   swizzled rows (128B)
  __shared__ _Float16 Vt[2][64][64];   // [buf][d][kv]   swizzled rows
  __shared__ _Float16 Pl[8][16][64];   // per-wave P [q][kv], swizzled rows
  const int t = threadIdx.x;
  const int l = t & 63, w = t >> 6;          // w in [0,8)
  const int lr = l & 15, lg = l >> 4;
  // XCD-grouping: id&7 -> XCD; per XCD: 4 heads x 16 q-blocks x 2 halves
  const int id = blockIdx.x;
  const int xc = id & 7, m_ = id >> 3;       // m_ in [0,128)
  const int kvh = m_ & 1;
  const int bh = xc + 8 * (m_ >> 5);
  const int qb = ((m_ >> 1) & 15) * 128 + w * 16;
  const int kvbase = kvh * (SEQ / 2);

  // Q fragments (B-operand: n=q=lr, k=d)
  const size_t qoff = ((size_t)bh * SEQ + qb + lr) * HD_;
  const f16x8 qf0 = *(const f16x8*)(qs + qoff + lg * 8);
  const f16x8 qf1 = *(const f16x8*)(qs + qoff + 32 + lg * 8);

  const _Float16* kbase = ks + (size_t)bh * SEQ * HD_;
  const _Float16* vbase = vt + (size_t)bh * HD_ * SEQ;

  // async staging: 512 threads cover the 64x64 tile in one pass each for K,V.
  // LDS dest linear (DMA rule); global SOURCE block pre-swizzled (T21).
  const int srow = t >> 3, scb = t & 7;      // srow in [0,64)
  auto stage = [&](const int buf, const int kv0) {
    gload_lds16(kbase + (size_t)(kv0 + srow) * HD_ + (scb ^ (srow & 7)) * 8,
                &Kt[buf][srow][scb * 8]);
    gload_lds16(vbase + (size_t)srow * SEQ + kv0 + (scb ^ (srow & 7)) * 8,
                &Vt[buf][srow][scb * 8]);
  };

  stage(0, kvbase);

  float mr = -1e30f, lsum = 0.f;
  f32x4 oacc[4];
#pragma unroll
  for (int n = 0; n < 4; ++n) oacc[n] = f32x4{0.f, 0.f, 0.f, 0.f};

  const int NT = SEQ / 128;  // 16 tiles per half
  for (int it = 0; it < NT; ++it) {
    const int cur = it & 1;
    __syncthreads();  // drains vmcnt: buf[cur] DMA complete; prev reads done
    if (it + 1 < NT) stage(cur ^ 1, kvbase + (it + 1) * 64);

    // S^T = K Q^T : lane holds S[kv=16*t4+4*lg+i][q=lr]   (base-2 logits)
    f32x4 sa[4];
    __builtin_amdgcn_s_setprio(1);
#pragma unroll
    for (int t4 = 0; t4 < 4; ++t4) {
      const int r = t4 * 16 + lr;
      const f16x8 kf0 = swzread(&Kt[cur][0][0], r, lg);
      const f16x8 kf1 = swzread(&Kt[cur][0][0], r, lg + 4);
      f32x4 s = mfma16(kf0, qf0, f32x4{0.f, 0.f, 0.f, 0.f});
      sa[t4] = mfma16(kf1, qf1, s);
    }
    __builtin_amdgcn_s_setprio(0);

    // online softmax (per-lane q-row), defer-max with THR=8 (base-2)
    float t01 = fmaxf(fmaxf(sa[0][0], sa[0][1]), fmaxf(sa[0][2], sa[0][3]));
    float t23 = fmaxf(fmaxf(sa[1][0], sa[1][1]), fmaxf(sa[1][2], sa[1][3]));
    float t45 = fmaxf(fmaxf(sa[2][0], sa[2][1]), fmaxf(sa[2][2], sa[2][3]));
    float t67 = fmaxf(fmaxf(sa[3][0], sa[3][1]), fmaxf(sa[3][2], sa[3][3]));
    float tm = fmaxf(fmaxf(t01, t23), fmaxf(t45, t67));
    tm = fmaxf(tm, __shfl_xor(tm, 16));
    tm = fmaxf(tm, __shfl_xor(tm, 32));

    if (__any(tm > mr + 8.0f)) {  // wave-uniform rescale
      const float nm = fmaxf(mr, tm);
      const float corr = exp2f(mr - nm);
      mr = nm;
      lsum *= corr;
      float cb4[4];
#pragma unroll
      for (int i = 0; i < 4; ++i)
        cb4[i] = __shfl(corr, (l & 48) + ((l >> 4) << 2) + i);
#pragma unroll
      for (int n = 0; n < 4; ++n)
#pragma unroll
        for (int i = 0; i < 4; ++i) oacc[n][i] *= cb4[i];
    }

    float ts = 0.f;
    char* plbase = (char*)&Pl[w][0][0];
#pragma unroll
    for (int t4 = 0; t4 < 4; ++t4) {
      f16x4 pp;
#pragma unroll
      for (int i = 0; i < 4; ++i) {
        const float p = exp2f(sa[t4][i] - mr);
        ts += p;
        pp[i] = (_Float16)p;
      }
      // P[q=lr][kv=t4*16+lg*4+i], swizzled row (XOR bits 4-6, 8B aligned)
      *(f16x4*)(plbase + lr * 128 + ((t4 * 32 + lg * 8) ^ ((lr & 7) << 4))) = pp;
    }
    ts += __shfl_xor(ts, 16);
    ts += __shfl_xor(ts, 32);
    lsum += ts;

    // O += P V (A=P[q][kv], B=V^T[d][kv])
    const f16x8 aP0 = swzread(&Pl[w][0][0], lr, lg);
    const f16x8 aP1 = swzread(&Pl[w][0][0], lr, lg + 4);
    __builtin_amdgcn_s_setprio(1);
#pragma unroll
    for (int n = 0; n < 4; ++n) {
      const int d = n * 16 + lr;
      const f16x8 bv0 = swzread(&Vt[cur][0][0], d, lg);
      const f16x8 bv1 = swzread(&Vt[cur][0][0], d, lg + 4);
      oacc[n] = mfma16(aP0, bv0, oacc[n]);
      oacc[n] = mfma16(aP1, bv1, oacc[n]);
    }
    __builtin_amdgcn_s_setprio(0);
  }

  // epilogue: write per-row (m, lsum) — every lane holds its lr's row values
  const size_t mlbase = ((size_t)kvh * 32 + bh) * SEQ + qb;
  if (l < 16) {
    marr[mlbase + l] = mr;
    larr[mlbase + l] = lsum;
  }
  // store unnormalized partial O as f16
  _Float16* opb = op + (size_t)kvh * BATCH * SEQ * EMB;
  const int b = bh >> 4, h = bh & 15;
#pragma unroll
  for (int n = 0; n < 4; ++n)
#pragma unroll
    for (int i = 0; i < 4; ++i) {
      const int row = qb + ((l >> 4) << 2) + i;
      opb[((size_t)b * SEQ + row) * EMB + h * HD_ + n * 16 + lr] =
          (_Float16)oacc[n][i];
    }
}

// ---------------- combine the two KV-halves ----------------
__global__ __launch_bounds__(256) void k_combine(const _Float16* __restrict__ op,
                                                 const float* __restrict__ marr,
                                                 const float* __restrict__ larr,
                                                 _Float16* __restrict__ ao) {
  const int idx = blockIdx.x * 256 + threadIdx.x;  // [0, B*S*E/8)
  const int e8 = idx & 127;                        // EMB/8 = 128
  const size_t rs = (size_t)(idx >> 7);            // b*SEQ + s
  const int h = e8 >> 3;
  const int b = (int)(rs >> 11);
  const size_t s = rs & (SEQ - 1);
  const size_t mi = ((size_t)b * NH + h) * SEQ + s;
  const float m1 = marr[mi], l1 = larr[mi];
  const float m2 = marr[(size_t)32 * SEQ + mi], l2 = larr[(size_t)32 * SEQ + mi];
  const float mx = fmaxf(m1, m2);
  const float w1 = exp2f(m1 - mx), w2 = exp2f(m2 - mx);
  const float inv = 1.0f / (l1 * w1 + l2 * w2);
  const f16x8 o1 = ((const f16x8*)op)[idx];
  const f16x8 o2 = ((const f16x8*)op)[idx + (BATCH * SEQ * EMB / 8)];
  f16x8 r;
#pragma unroll
  for (int j = 0; j < 8; ++j)
    r[j] = (_Float16)(((float)o1[j] * w1 + (float)o2[j] * w2) * inv);
  ((f16x8*)ao)[idx] = r;
}

extern "C" void kernel_launch(void* const* d_in, const int* in_sizes, int n_in,
                              void* d_out, int out_size, void* d_ws, size_t ws_size,
                              hipStream_t stream) {
  const float* query = (const float*)d_in[0];
  const float* Wqkv = (const float*)d_in[3];
  const float* bqkv = (const float*)d_in[4];
  const float* Wproj = (const float*)d_in[5];
  const float* bproj = (const float*)d_in[6];
  float* out = (float*)d_out;

  char* ws = (char*)d_ws;
  const size_t MB = 1024 * 1024;
  _Float16* q_hi    = (_Float16*)(ws + 0);         // 8MB; dead after QKV GEMM
  _Float16* q_lo    = (_Float16*)(ws + 8 * MB);    // 8MB; dead after QKV GEMM
  _Float16* Wqkv_t  = (_Float16*)(ws + 16 * MB);   // 6MB f16 (rows: q|k|v)
  _Float16* q_s     = (_Float16*)(ws + 24 * MB);   // 8MB [32][2048][64]
  _Float16* k_s     = (_Float16*)(ws + 32 * MB);   // 8MB
  _Float16* v_t     = (_Float16*)(ws + 40 * MB);   // 8MB [32][64][2048]
  _Float16* op      = (_Float16*)(ws + 0);         // 16MB partials (alias q_hi+q_lo)
  _Float16* Wproj_t = (_Float16*)(ws + 48 * MB);   // 2MB
  float*    marr    = (float*)(ws + 50 * MB);      // 512KB [2][32][2048]
  float*    larr    = (float*)(ws + 50 * MB + 512 * 1024);  // 512KB
  _Float16* a_o     = (_Float16*)(ws + 51 * MB);   // 8MB

  const int M = BATCH * SEQ;  // 4096
  k_convert_split<<<(M * EMB / 4 + 255) / 256, 256, 0, stream>>>(query, q_hi, q_lo,
                                                                 M * EMB / 4);
  k_transpose<1><<<dim3(3 * EMB / 32, EMB / 32), 256, 0, stream>>>(Wqkv, Wqkv_t, EMB,
                                                                   3 * EMB);
  k_gemm_qkv<<<dim3(24, M / 128), 256, 0, stream>>>(q_hi, q_lo, Wqkv_t, bqkv, q_s, k_s,
                                                    v_t);
  k_transpose<0><<<dim3(EMB / 32, EMB / 32), 256, 0, stream>>>(Wproj, Wproj_t, EMB, EMB);
  k_attn<<<dim3(1024), 512, 0, stream>>>(q_s, k_s, v_t, op, marr, larr);
  k_combine<<<dim3(BATCH * SEQ * EMB / 8 / 256), 256, 0, stream>>>(op, marr, larr, a_o);
  k_gemm_proj<<<dim3(EMB / 128, M / 128), 256, 0, stream>>>(a_o, Wproj_t, bproj, out);
}